// Round 1
// baseline (488.442 us; speedup 1.0000x reference)
//
#include <hip/hip_runtime.h>

// SSIM3D: imgs (4,1,128,128,128) fp32, 11^3 Gaussian window (separable),
// output = scalar mean of SSIM map.
//
// Strategy: 5 fields (mu1, mu2, E[x^2], E[y^2], E[xy] pre-subtraction) each
// convolved separably along x, y, z with the 1D Gaussian; then fused SSIM +
// mean reduction. Processed one batch element at a time so workspace needs
// only 2 ping-pong buffers of 5 fields (84 MB total).

#define DD 128
#define HH 128
#define WW 128
#define S  (DD*HH*WW)      // 2097152 elements per batch item per field
#define NBATCH 4
#define C1_ 0.0001f
#define C2_ 0.0009f

__device__ __forceinline__ void make_g(float* g) {
    // matches _gaussian_1d(11, 1.5): exp(-(i-5)^2 / (2*1.5^2)), normalized
    float s = 0.f;
#pragma unroll
    for (int i = 0; i < 11; ++i) {
        float d = (float)(i - 5);
        g[i] = expf(-d * d / 4.5f);
        s += g[i];
    }
    float inv = 1.f / s;
#pragma unroll
    for (int i = 0; i < 11; ++i) g[i] *= inv;
}

// Pass 1: conv along x (contiguous), fused with forming the 5 fields.
// One block per row (z,y); 128 threads = one x each.
__global__ void ssim_pass1_x(const float* __restrict__ i1,
                             const float* __restrict__ i2,
                             float* __restrict__ out) {
    __shared__ float s1[WW], s2[WW];
    float g[11]; make_g(g);
    int row = blockIdx.x;            // 0 .. DD*HH-1
    int x = threadIdx.x;             // 0 .. 127
    const float* p1 = i1 + (size_t)row * WW;
    const float* p2 = i2 + (size_t)row * WW;
    s1[x] = p1[x];
    s2[x] = p2[x];
    __syncthreads();
    float u1 = 0, u2 = 0, a11 = 0, a22 = 0, a12 = 0;
#pragma unroll
    for (int k = 0; k < 11; ++k) {
        int xx = x + k - 5;
        if (xx >= 0 && xx < WW) {
            float a = s1[xx], b = s2[xx], w = g[k];
            u1  += w * a;
            u2  += w * b;
            a11 += w * a * a;
            a22 += w * b * b;
            a12 += w * a * b;
        }
    }
    size_t idx = (size_t)row * WW + x;
    out[0 * (size_t)S + idx] = u1;
    out[1 * (size_t)S + idx] = u2;
    out[2 * (size_t)S + idx] = a11;
    out[3 * (size_t)S + idx] = a22;
    out[4 * (size_t)S + idx] = a12;
}

// Pass 2: conv along y. Block handles (field f, z-slice, x-half 64 wide);
// LDS tile 128(y) x 64(x) = 32 KB.
__global__ void ssim_pass2_y(const float* __restrict__ in,
                             float* __restrict__ out) {
    __shared__ float t[HH][64];
    float g[11]; make_g(g);
    int b = blockIdx.x;
    int xt = b & 1;
    int z  = (b >> 1) & 127;
    int f  = b >> 8;
    const float* ip = in  + (size_t)f * S + (size_t)z * HH * WW + xt * 64;
    float*       op = out + (size_t)f * S + (size_t)z * HH * WW + xt * 64;
    for (int i = threadIdx.x; i < HH * 64; i += 256) {
        int y = i >> 6, x = i & 63;
        t[y][x] = ip[(size_t)y * WW + x];
    }
    __syncthreads();
    for (int i = threadIdx.x; i < HH * 64; i += 256) {
        int y = i >> 6, x = i & 63;
        float acc = 0.f;
#pragma unroll
        for (int k = 0; k < 11; ++k) {
            int yy = y + k - 5;
            if (yy >= 0 && yy < HH) acc += g[k] * t[yy][x];
        }
        op[(size_t)y * WW + x] = acc;
    }
}

// Pass 3: conv along z. Block handles (field f, y-row, x-half);
// LDS tile 128(z) x 64(x) = 32 KB.
__global__ void ssim_pass3_z(const float* __restrict__ in,
                             float* __restrict__ out) {
    __shared__ float t[DD][64];
    float g[11]; make_g(g);
    int b = blockIdx.x;
    int xt = b & 1;
    int y  = (b >> 1) & 127;
    int f  = b >> 8;
    const float* ip = in  + (size_t)f * S + (size_t)y * WW + xt * 64;
    float*       op = out + (size_t)f * S + (size_t)y * WW + xt * 64;
    for (int i = threadIdx.x; i < DD * 64; i += 256) {
        int z = i >> 6, x = i & 63;
        t[z][x] = ip[(size_t)z * HH * WW + x];
    }
    __syncthreads();
    for (int i = threadIdx.x; i < DD * 64; i += 256) {
        int z = i >> 6, x = i & 63;
        float acc = 0.f;
#pragma unroll
        for (int k = 0; k < 11; ++k) {
            int zz = z + k - 5;
            if (zz >= 0 && zz < DD) acc += g[k] * t[zz][x];
        }
        op[(size_t)z * HH * WW + x] = acc;
    }
}

// Pass 4: SSIM map + per-block reduction. 1024 blocks x 256 threads x 8 elems.
__global__ void ssim_pass4_map(const float* __restrict__ f5,
                               float* __restrict__ partial) {
    int tid = threadIdx.x;
    int base = blockIdx.x * 2048;
    float sum = 0.f;
#pragma unroll
    for (int it = 0; it < 8; ++it) {
        int idx = base + it * 256 + tid;
        float m1  = f5[0 * (size_t)S + idx];
        float m2  = f5[1 * (size_t)S + idx];
        float p11 = f5[2 * (size_t)S + idx];
        float p22 = f5[3 * (size_t)S + idx];
        float p12 = f5[4 * (size_t)S + idx];
        float m1s = m1 * m1, m2s = m2 * m2, m12 = m1 * m2;
        float v1 = p11 - m1s, v2 = p22 - m2s, cv = p12 - m12;
        float num = (2.f * m12 + C1_) * (2.f * cv + C2_);
        float den = (m1s + m2s + C1_) * (v1 + v2 + C2_);
        sum += num / den;
    }
    // wave64 shuffle reduce, then cross-wave via LDS
#pragma unroll
    for (int off = 32; off > 0; off >>= 1)
        sum += __shfl_down(sum, off, 64);
    __shared__ float wsum[4];
    int lane = tid & 63, wid = tid >> 6;
    if (lane == 0) wsum[wid] = sum;
    __syncthreads();
    if (tid == 0)
        partial[blockIdx.x] = wsum[0] + wsum[1] + wsum[2] + wsum[3];
}

// Final: reduce all partials in double, write mean.
__global__ void ssim_final(const float* __restrict__ partial, int n,
                           float* __restrict__ out, double inv_count) {
    int tid = threadIdx.x;
    double s = 0.0;
    for (int i = tid; i < n; i += 256) s += (double)partial[i];
#pragma unroll
    for (int off = 32; off > 0; off >>= 1)
        s += __shfl_down(s, off, 64);
    __shared__ double wsum[4];
    int lane = tid & 63, wid = tid >> 6;
    if (lane == 0) wsum[wid] = s;
    __syncthreads();
    if (tid == 0)
        out[0] = (float)((wsum[0] + wsum[1] + wsum[2] + wsum[3]) * inv_count);
}

extern "C" void kernel_launch(void* const* d_in, const int* in_sizes, int n_in,
                              void* d_out, int out_size, void* d_ws, size_t ws_size,
                              hipStream_t stream) {
    const float* img1 = (const float*)d_in[0];
    const float* img2 = (const float*)d_in[1];
    // d_in[2] = window, unused: separable Gaussian recomputed in-kernel.
    float* out = (float*)d_out;

    float* bufA = (float*)d_ws;                        // 5 fields
    float* bufB = bufA + 5 * (size_t)S;                // 5 fields
    float* partials = bufB + 5 * (size_t)S;            // 4*1024 floats

    const int nPart = S / 2048;                        // 1024 blocks per batch
    for (int n = 0; n < NBATCH; ++n) {
        const float* i1 = img1 + (size_t)n * S;
        const float* i2 = img2 + (size_t)n * S;
        ssim_pass1_x<<<DD * HH, WW, 0, stream>>>(i1, i2, bufA);
        ssim_pass2_y<<<5 * 128 * 2, 256, 0, stream>>>(bufA, bufB);
        ssim_pass3_z<<<5 * 128 * 2, 256, 0, stream>>>(bufB, bufA);
        ssim_pass4_map<<<nPart, 256, 0, stream>>>(bufA, partials + n * nPart);
    }
    ssim_final<<<1, 256, 0, stream>>>(partials, NBATCH * nPart, out,
                                      1.0 / ((double)S * NBATCH));
}

// Round 2
// 252.693 us; speedup vs baseline: 1.9329x; 1.9329x over previous
//
#include <hip/hip_runtime.h>

// SSIM3D, (4,1,128,128,128) fp32, separable 11-tap Gaussian, scalar mean out.
//
// 3 dispatches:
//  A: x-conv + y-conv fused (sliding-window accs over y), 5 fields -> ws
//  B: z-conv + SSIM map + block reduction (sliding-window accs over z)
//  C: final reduce of 2048 partials
//
// Sliding-window trick: output o needs inputs o-5..o+5. Keep 11 accumulators
// per field; input at step contributes to outputs o = step-10+j (j=0..10)
// with weight g[10-j], into slot o mod 11 == (t+j+1)%11 for step = 11*blk+t
// -- static index under unroll-by-11, so accs live in registers.
// Out-of-range taps are killed by zeroing the weight (branchless).

#define DD 128
#define SLICE (128*128)        // 16384
#define S  (DD*SLICE)          // 2097152 per field per batch
#define NBATCH 4
#define C1_ 0.0001f
#define C2_ 0.0009f

__device__ __forceinline__ void make_g(float* g) {
    float s = 0.f;
#pragma unroll
    for (int i = 0; i < 11; ++i) {
        float d = (float)(i - 5);
        g[i] = __expf(-d * d / 4.5f);
        s += g[i];
    }
    float inv = 1.f / s;
#pragma unroll
    for (int i = 0; i < 11; ++i) g[i] *= inv;
}

// ---------------- Kernel A: x-conv + y-conv, walk y ----------------
// grid: 4n * 128z * 4yc = 2048 blocks of 64 threads (1 wave).
// thread q owns x = 2q, 2q+1.
// LDS: 11 staged rows * 2 imgs * 140 floats (6 left-pad zeros, 5+1 right).
__global__ __launch_bounds__(64, 2)
void ssimA(const float* __restrict__ img1, const float* __restrict__ img2,
           float* __restrict__ fields) {
    __shared__ float rows[11][2][140];
    float g[11]; make_g(g);
    const int tid = threadIdx.x;
    const int q2 = tid * 2;
    const int b = blockIdx.x;
    const int yc = b & 3, z = (b >> 2) & 127, n = b >> 9;
    const int y0 = yc * 32;
    const float* p1 = img1 + (size_t)n * S + (size_t)z * SLICE;
    const float* p2 = img2 + (size_t)n * S + (size_t)z * SLICE;
    float* fb = fields + (size_t)n * 5 * S + (size_t)z * SLICE + q2;

    // zero the pads once (single wave: LDS ops are ordered, no barrier)
#pragma unroll
    for (int r = 0; r < 11; ++r) {
        if (tid < 6)  { rows[r][0][tid] = 0.f; rows[r][1][tid] = 0.f; }
        if (tid >= 58){ rows[r][0][tid + 76] = 0.f; rows[r][1][tid + 76] = 0.f; }
    }

    float acc[2][5][11];
#pragma unroll
    for (int p = 0; p < 2; ++p)
#pragma unroll
        for (int f = 0; f < 5; ++f)
#pragma unroll
            for (int s2 = 0; s2 < 11; ++s2) acc[p][f][s2] = 0.f;

#pragma unroll 1
    for (int blk = 0; blk < 4; ++blk) {
        // ---- load phase: 11 rows (clamped, unguarded -> latency batched)
#pragma unroll
        for (int t = 0; t < 11; ++t) {
            int step = blk * 11 + t;
            int y_in = y0 + step - 5;
            int ycl = min(max(y_in, 0), 127);
            float2 a = *(const float2*)(p1 + (size_t)ycl * 128 + q2);
            float2 c = *(const float2*)(p2 + (size_t)ycl * 128 + q2);
            *(float2*)&rows[t][0][6 + q2] = a;
            *(float2*)&rows[t][1][6 + q2] = c;
        }
        // ---- compute phase
#pragma unroll
        for (int t = 0; t < 11; ++t) {
            int step = blk * 11 + t;
            if (step >= 42) continue;           // uniform (only last blk)
            int y_in = y0 + step - 5;
            bool row_ok = (y_in >= 0) && (y_in < 128);

            float v1[14], v2[14];
#pragma unroll
            for (int m = 0; m < 7; ++m) {
                *(float2*)&v1[2 * m] = *(const float2*)&rows[t][0][q2 + 2 * m];
                *(float2*)&v2[2 * m] = *(const float2*)&rows[t][1][q2 + 2 * m];
            }
            // x-conv of the 5 fields for both points
            float u1[2] = {0,0}, u2[2] = {0,0};
            float a11[2] = {0,0}, a22[2] = {0,0}, a12[2] = {0,0};
#pragma unroll
            for (int k = 0; k < 11; ++k) {
                float w = g[k];
#pragma unroll
                for (int o = 0; o < 2; ++o) {
                    float a_ = v1[1 + o + k], b_ = v2[1 + o + k];
                    float ta = w * a_, tb = w * b_;
                    u1[o] += ta; u2[o] += tb;
                    a11[o] = fmaf(ta, a_, a11[o]);
                    a12[o] = fmaf(ta, b_, a12[o]);
                    a22[o] = fmaf(tb, b_, a22[o]);
                }
            }
            // y-accumulate: slot (t+j+1)%11 is static
#pragma unroll
            for (int j = 0; j < 11; ++j) {
                int oo = step - 10 + j;
                float w = (row_ok && oo >= 0 && oo < 32) ? g[10 - j] : 0.f;
                const int sl = (t + j + 1) % 11;
                acc[0][0][sl] = fmaf(w, u1[0],  acc[0][0][sl]);
                acc[1][0][sl] = fmaf(w, u1[1],  acc[1][0][sl]);
                acc[0][1][sl] = fmaf(w, u2[0],  acc[0][1][sl]);
                acc[1][1][sl] = fmaf(w, u2[1],  acc[1][1][sl]);
                acc[0][2][sl] = fmaf(w, a11[0], acc[0][2][sl]);
                acc[1][2][sl] = fmaf(w, a11[1], acc[1][2][sl]);
                acc[0][3][sl] = fmaf(w, a22[0], acc[0][3][sl]);
                acc[1][3][sl] = fmaf(w, a22[1], acc[1][3][sl]);
                acc[0][4][sl] = fmaf(w, a12[0], acc[0][4][sl]);
                acc[1][4][sl] = fmaf(w, a12[1], acc[1][4][sl]);
            }
            // emit output y_out = y0 + step - 10
            if (step >= 10) {
                const int es = (t + 1) % 11;    // static
                int y_out = y0 + step - 10;
                size_t ro = (size_t)y_out * 128;
#pragma unroll
                for (int f = 0; f < 5; ++f) {
                    float2 ov = make_float2(acc[0][f][es], acc[1][f][es]);
                    *(float2*)(fb + (size_t)f * S + ro) = ov;
                    acc[0][f][es] = 0.f; acc[1][f][es] = 0.f;
                }
            }
        }
    }
}

// ---------------- Kernel B: z-conv + map + reduce, walk z ----------------
// grid: 4n * 128y * 4zc = 2048 blocks of 64 threads.
__global__ __launch_bounds__(64, 2)
void ssimB(const float* __restrict__ fields, float* __restrict__ partials) {
    float g[11]; make_g(g);
    const int tid = threadIdx.x;
    const int q2 = tid * 2;
    const int b = blockIdx.x;
    const int zc = b & 3, y = (b >> 2) & 127, n = b >> 9;
    const int z0 = zc * 32;
    const float* P0 = fields + ((size_t)(n * 5 + 0)) * S + (size_t)y * 128 + q2;
    const float* P1 = fields + ((size_t)(n * 5 + 1)) * S + (size_t)y * 128 + q2;
    const float* P2 = fields + ((size_t)(n * 5 + 2)) * S + (size_t)y * 128 + q2;
    const float* P3 = fields + ((size_t)(n * 5 + 3)) * S + (size_t)y * 128 + q2;
    const float* P4 = fields + ((size_t)(n * 5 + 4)) * S + (size_t)y * 128 + q2;

    float acc[2][5][11];
#pragma unroll
    for (int p = 0; p < 2; ++p)
#pragma unroll
        for (int f = 0; f < 5; ++f)
#pragma unroll
            for (int s2 = 0; s2 < 11; ++s2) acc[p][f][s2] = 0.f;

    float sum = 0.f;

#pragma unroll 1
    for (int blk = 0; blk < 4; ++blk) {
#pragma unroll
        for (int t = 0; t < 11; ++t) {
            int step = blk * 11 + t;
            int z_in = z0 + step - 5;
            int zcl = min(max(z_in, 0), 127);
            bool row_ok = (z_in >= 0) && (z_in < 128);
            size_t off = (size_t)zcl * SLICE;
            float2 f0 = *(const float2*)(P0 + off);
            float2 f1 = *(const float2*)(P1 + off);
            float2 f2 = *(const float2*)(P2 + off);
            float2 f3 = *(const float2*)(P3 + off);
            float2 f4 = *(const float2*)(P4 + off);
            if (step >= 42) continue;           // uniform
#pragma unroll
            for (int j = 0; j < 11; ++j) {
                int oo = step - 10 + j;
                float w = (row_ok && oo >= 0 && oo < 32) ? g[10 - j] : 0.f;
                const int sl = (t + j + 1) % 11;
                acc[0][0][sl] = fmaf(w, f0.x, acc[0][0][sl]);
                acc[1][0][sl] = fmaf(w, f0.y, acc[1][0][sl]);
                acc[0][1][sl] = fmaf(w, f1.x, acc[0][1][sl]);
                acc[1][1][sl] = fmaf(w, f1.y, acc[1][1][sl]);
                acc[0][2][sl] = fmaf(w, f2.x, acc[0][2][sl]);
                acc[1][2][sl] = fmaf(w, f2.y, acc[1][2][sl]);
                acc[0][3][sl] = fmaf(w, f3.x, acc[0][3][sl]);
                acc[1][3][sl] = fmaf(w, f3.y, acc[1][3][sl]);
                acc[0][4][sl] = fmaf(w, f4.x, acc[0][4][sl]);
                acc[1][4][sl] = fmaf(w, f4.y, acc[1][4][sl]);
            }
            if (step >= 10) {
                const int es = (t + 1) % 11;    // static
#pragma unroll
                for (int p = 0; p < 2; ++p) {
                    float m1 = acc[p][0][es], m2 = acc[p][1][es];
                    float p11 = acc[p][2][es], p22 = acc[p][3][es];
                    float p12 = acc[p][4][es];
                    float m1s = m1 * m1, m2s = m2 * m2, m12 = m1 * m2;
                    float v1 = p11 - m1s, v2 = p22 - m2s, cv = p12 - m12;
                    float num = (2.f * m12 + C1_) * (2.f * cv + C2_);
                    float den = (m1s + m2s + C1_) * (v1 + v2 + C2_);
                    sum += num / den;
#pragma unroll
                    for (int f = 0; f < 5; ++f) acc[p][f][es] = 0.f;
                }
            }
        }
    }
    // wave64 reduce
#pragma unroll
    for (int o = 32; o > 0; o >>= 1) sum += __shfl_down(sum, o, 64);
    if (tid == 0) partials[blockIdx.x] = sum;
}

// ---------------- final reduce ----------------
__global__ void ssim_final(const float* __restrict__ partial, int n,
                           float* __restrict__ out, double inv_count) {
    int tid = threadIdx.x;
    double s = 0.0;
    for (int i = tid; i < n; i += 256) s += (double)partial[i];
#pragma unroll
    for (int o = 32; o > 0; o >>= 1) s += __shfl_down(s, o, 64);
    __shared__ double wsum[4];
    int lane = tid & 63, wid = tid >> 6;
    if (lane == 0) wsum[wid] = s;
    __syncthreads();
    if (tid == 0)
        out[0] = (float)((wsum[0] + wsum[1] + wsum[2] + wsum[3]) * inv_count);
}

extern "C" void kernel_launch(void* const* d_in, const int* in_sizes, int n_in,
                              void* d_out, int out_size, void* d_ws, size_t ws_size,
                              hipStream_t stream) {
    const float* img1 = (const float*)d_in[0];
    const float* img2 = (const float*)d_in[1];
    float* out = (float*)d_out;

    float* fields   = (float*)d_ws;                    // 20*S floats (167.8 MB)
    float* partials = fields + 20 * (size_t)S;         // 2048 floats

    ssimA<<<2048, 64, 0, stream>>>(img1, img2, fields);
    ssimB<<<2048, 64, 0, stream>>>(fields, partials);
    ssim_final<<<1, 256, 0, stream>>>(partials, 2048, out,
                                      1.0 / ((double)S * NBATCH));
}